// Round 9
// baseline (348.686 us; speedup 1.0000x reference)
//
#include <hip/hip_runtime.h>
#include <hip/hip_bf16.h>
#include <math.h>

#define HIDDEN 1024
#define ADIM 32
#define NEMB 32
#define BB 128
#define TT 16
#define NROWS (BB*TT)   // 2048
#define KSPLIT 4

// LDS B layout: [gn:64][oct:4][n16:16 x bf16x8-in-k], u16 units
#define OCT_STRIDE 136                  // 128 data + 8 pad
#define GN_STRIDE  552                  // 4*136 + 8 pad
#define BS_U16     (64 * GN_STRIDE)     // 35328 u16 = 70656 B per buffer

typedef float f32x4 __attribute__((ext_vector_type(4)));
typedef short bf16x8 __attribute__((ext_vector_type(8)));
typedef unsigned short u16;

static __device__ __forceinline__ u16 f2bf(float f) {
    union { __hip_bfloat16 h; u16 u; } cv;
    cv.h = __float2bfloat16(f);   // RNE
    return cv.u;
}

// raw barrier: completes LDS ops, leaves global loads in flight
#define BARRIER() do { \
    asm volatile("s_waitcnt lgkmcnt(0)" ::: "memory"); \
    __builtin_amdgcn_s_barrier(); \
    asm volatile("" ::: "memory"); \
} while (0)

// ws layout:
//  [0, 4096)   : meta: [0..31]=cnt, [32..63]=off, [64..191]=blist,
//                [192]=ntiles, [200+4i..]=tiles (row0, rows, e)
//  xg  @ 4096  : 2048 x 2048 bf16 (8MB) grouped rows
//  yg  @ +8MB  : 2048 x 1024 bf16 (4MB) grouped rows
//  pbuf @ +4MB : KSPLIT x 2048 x 1024 f32 (32MB)

__global__ void prep_kernel(const int* __restrict__ cat, int* __restrict__ meta) {
    __shared__ int c[BB];
    int tid = threadIdx.x;
    if (tid < BB) c[tid] = cat[tid];
    __syncthreads();
    if (tid == 0) {
        int cnt[NEMB];
        for (int e = 0; e < NEMB; e++) cnt[e] = 0;
        for (int b = 0; b < BB; b++) cnt[c[b]]++;
        int off = 0;
        for (int e = 0; e < NEMB; e++) { meta[e] = cnt[e]; meta[32 + e] = off; off += cnt[e]; }
        int pos[NEMB];
        for (int e = 0; e < NEMB; e++) pos[e] = meta[32 + e];
        for (int b = 0; b < BB; b++) { int e = c[b]; meta[64 + pos[e]] = b; pos[e]++; }
        int nt = 0;
        for (int e = 0; e < NEMB; e++) {
            int Me = cnt[e] * TT;
            int base = meta[32 + e] * TT;
            for (int mb = 0; mb * 64 < Me; mb++) {
                int rows = Me - mb * 64; if (rows > 64) rows = 64;
                meta[200 + 4 * nt + 0] = base + mb * 64;
                meta[200 + 4 * nt + 1] = rows;
                meta[200 + 4 * nt + 2] = e;
                nt++;
            }
        }
        meta[192] = nt;   // <= 56
    }
}

// Layer 1 + PE, written grouped as bf16.
__global__ __launch_bounds__(256) void build_x_kernel(
    const float* __restrict__ actions, const int* __restrict__ timesteps,
    const int* __restrict__ cat_ids, const float* __restrict__ W1,
    const float* __restrict__ b1, const int* __restrict__ meta,
    u16* __restrict__ xg)
{
    int sb = blockIdx.x;
    int b  = meta[64 + sb];
    int e  = cat_ids[b];
    int tid = threadIdx.x;

    __shared__ float act[TT][ADIM];
    for (int i = tid; i < TT * ADIM; i += 256)
        act[i / ADIM][i % ADIM] = actions[(size_t)b * TT * ADIM + i];
    __syncthreads();

    float tau = (float)timesteps[b];

    for (int h = tid; h < HIDDEN; h += 256) {
        float acc[TT];
        #pragma unroll
        for (int t = 0; t < TT; t++) acc[t] = 0.f;
        for (int d = 0; d < ADIM; d++) {
            float w = W1[((size_t)e * ADIM + d) * HIDDEN + h];
            #pragma unroll
            for (int t = 0; t < TT; t++) acc[t] += act[t][d] * w;
        }
        float bv = b1[(size_t)e * HIDDEN + h];
        for (int t = 0; t < TT; t++)
            xg[(size_t)(sb * TT + t) * 2048 + h] = f2bf(acc[t] + bv);
    }

    for (int j = tid; j < HIDDEN; j += 256) {
        int i = j >> 1;
        float arg = tau * expf((float)i * -0.017988946f);
        float v = (j & 1) ? cosf(arg) : sinf(arg);
        u16 bv = f2bf(v);
        for (int t = 0; t < TT; t++)
            xg[(size_t)(sb * TT + t) * 2048 + 1024 + j] = bv;
    }
}

// Full-row streaming grouped GEMM with split-K partials.
// bid = kc(4, low bits) + 4*slot. Block: 1024 thr (16 waves, 2m x 8n),
// tile 64m x 1024n, BK=32. Staging reads COMPLETE 4KB W rows: per
// instruction-step 4 full rows (256 thr x 16B each), rows ascending ->
// pure sequential DRAM streams. Two staging substeps of 16 rows keep
// stage regs at 16. Double-buffered LDS (138KB), counted-vmcnt waits,
// lgkm-only barriers, A (bf16 from xg/L2) ping-pong one phase ahead.
__global__ __launch_bounds__(1024, 1) void gemm_rowstream(
    const u16* __restrict__ X,        // grouped rows bf16, ld = ldx
    const float* __restrict__ W,      // (NEMB, Kdim, 1024) f32
    float* __restrict__ pbuf,         // KSPLIT x 2048 x 1024 f32
    const int* __restrict__ meta,
    int Kdim, int ldx)
{
    int bid  = blockIdx.x;
    int kc   = bid & 3;
    int slot = bid >> 2;
    if (slot >= meta[192]) return;
    int row0      = meta[200 + 4 * slot + 0];
    int rowsValid = meta[200 + 4 * slot + 1];
    int e         = meta[200 + 4 * slot + 2];

    int KC  = Kdim / KSPLIT;
    int kc0 = kc * KC;
    int nT  = KC >> 5;             // K-steps of 32: 16 (L2) or 8 (L3); even

    __shared__ u16 Bs[2][BS_U16];  // 138 KB

    int tid  = threadIdx.x;
    int lane = tid & 63;
    int wid  = tid >> 6;
    int wm   = wid & 1;            // m-half (32 rows)
    int wn   = wid >> 1;           // n-slice (128 cols)
    int l15  = lane & 15;
    int kh   = lane >> 4;          // k-octet of the wave's fragment

    const float* Wp = W + (size_t)e * Kdim * 1024;

    // staging map: n4 = n-quad (0..255), ko2 = row-quad group (0..3)
    int n4  = tid & 255;
    int ko2 = tid >> 8;

    f32x4  v0[4], v1[4];           // two 16-row substeps (16 VGPR each)
    bf16x8 a0[2], a1[2];           // A frags ping-pong

    f32x4 acc[2][8];               // [mi][g] : 64 VGPR
    #pragma unroll
    for (int mi = 0; mi < 2; mi++)
        #pragma unroll
        for (int g = 0; g < 8; g++)
            acc[mi][g] = (f32x4){0.f, 0.f, 0.f, 0.f};

    // substep s reads rows kc0 + kt*32 + s*16 + ko2*4 + r (r=0..3), cols n4*4..+3
    #define LOADB(vv, kt, s) do { \
        _Pragma("unroll") \
        for (int r = 0; r < 4; r++) \
            vv[r] = *(const f32x4*)&Wp[(size_t)(kc0 + (kt) * 32 + (s) * 16 + ko2 * 4 + r) * 1024 + n4 * 4]; \
    } while (0)

    // LDS idx (u16): gn*552 + oct*136 + (n&15)*8 + within-oct k-offset
    #define WRITEB(vv, s, c) do { \
        _Pragma("unroll") \
        for (int j = 0; j < 4; j++) { \
            int n = n4 * 4 + j; \
            ushort4 w = make_ushort4(f2bf(vv[0][j]), f2bf(vv[1][j]), \
                                     f2bf(vv[2][j]), f2bf(vv[3][j])); \
            *(ushort4*)&Bs[c][(n >> 4) * GN_STRIDE + ((s) * 2 + (ko2 >> 1)) * OCT_STRIDE \
                              + (n & 15) * 8 + (ko2 & 1) * 4] = w; \
        } \
    } while (0)

    #define LOADA(ag, kt) do { \
        _Pragma("unroll") \
        for (int mi = 0; mi < 2; mi++) { \
            int m = row0 + wm * 32 + mi * 16 + l15; \
            if (m > NROWS - 1) m = NROWS - 1; \
            ag[mi] = *(const bf16x8*)&X[(size_t)m * ldx + kc0 + (kt) * 32 + kh * 8]; \
        } \
    } while (0)

    #define COMPUTE(c, ag) do { \
        _Pragma("unroll") \
        for (int g = 0; g < 8; g++) { \
            int gn = wn * 8 + g; \
            bf16x8 bf = *(const bf16x8*)&Bs[c][gn * GN_STRIDE + kh * OCT_STRIDE + l15 * 8]; \
            _Pragma("unroll") \
            for (int mi = 0; mi < 2; mi++) \
                acc[mi][g] = __builtin_amdgcn_mfma_f32_16x16x32_bf16(ag[mi], bf, acc[mi][g], 0, 0, 0); \
        } \
    } while (0)

    // prologue
    LOADB(v0, 0, 0);
    LOADB(v1, 0, 1);
    LOADA(a0, 0);

    for (int kt = 0; kt < nT; kt += 2) {
        // step kt -> LDS buf 0
        WRITEB(v0, 0, 0);                    // waits only v0's 4 loads
        WRITEB(v1, 1, 0);                    // waits only v1's 4 loads
        if (kt + 1 < nT) { LOADB(v0, kt + 1, 0); LOADB(v1, kt + 1, 1); LOADA(a1, kt + 1); }
        BARRIER();
        COMPUTE(0, a0);
        // step kt+1 -> LDS buf 1
        WRITEB(v0, 0, 1);
        WRITEB(v1, 1, 1);
        if (kt + 2 < nT) { LOADB(v0, kt + 2, 0); LOADB(v1, kt + 2, 1); LOADA(a0, kt + 2); }
        BARRIER();
        COMPUTE(1, a1);
    }

    #undef LOADB
    #undef WRITEB
    #undef LOADA
    #undef COMPUTE

    // partial store
    float* pb = pbuf + (size_t)kc * NROWS * 1024;
    #pragma unroll
    for (int mi = 0; mi < 2; mi++) {
        #pragma unroll
        for (int r = 0; r < 4; r++) {
            int m = wm * 32 + mi * 16 + kh * 4 + r;
            if (m < rowsValid) {
                float* dst = pb + (size_t)(row0 + m) * 1024 + wn * 128 + l15;
                #pragma unroll
                for (int g = 0; g < 8; g++)
                    dst[g * 16] = acc[mi][g][r];
            }
        }
    }
}

// yg = bf16(swish(sum_kc pbuf + b2)), grouped rows
__global__ __launch_bounds__(256) void reduce_mid(
    const float* __restrict__ pbuf, const float* __restrict__ b2,
    const int* __restrict__ meta, const int* __restrict__ cat,
    u16* __restrict__ yg)
{
    int r = blockIdx.x;
    int e = cat[meta[64 + (r >> 4)]];
    int c = threadIdx.x * 4;
    f32x4 s = *(const f32x4*)&pbuf[(size_t)r * 1024 + c];
    #pragma unroll
    for (int kc = 1; kc < KSPLIT; kc++) {
        f32x4 t = *(const f32x4*)&pbuf[(size_t)kc * NROWS * 1024 + (size_t)r * 1024 + c];
        s = s + t;
    }
    f32x4 bb = *(const f32x4*)&b2[(size_t)e * 1024 + c];
    ushort4 o;
    float h0 = s[0] + bb[0]; o.x = f2bf(h0 / (1.f + expf(-h0)));
    float h1 = s[1] + bb[1]; o.y = f2bf(h1 / (1.f + expf(-h1)));
    float h2 = s[2] + bb[2]; o.z = f2bf(h2 / (1.f + expf(-h2)));
    float h3 = s[3] + bb[3]; o.w = f2bf(h3 / (1.f + expf(-h3)));
    *(ushort4*)&yg[(size_t)r * 1024 + c] = o;
}

// out[natural] = sum_kc pbuf + b3
__global__ __launch_bounds__(256) void reduce_out(
    const float* __restrict__ pbuf, const float* __restrict__ b3,
    const int* __restrict__ meta, const int* __restrict__ cat,
    float* __restrict__ out)
{
    int r = blockIdx.x;
    int bnat = meta[64 + (r >> 4)];
    int e = cat[bnat];
    int c = threadIdx.x * 4;
    f32x4 s = *(const f32x4*)&pbuf[(size_t)r * 1024 + c];
    #pragma unroll
    for (int kc = 1; kc < KSPLIT; kc++) {
        f32x4 t = *(const f32x4*)&pbuf[(size_t)kc * NROWS * 1024 + (size_t)r * 1024 + c];
        s = s + t;
    }
    f32x4 bb = *(const f32x4*)&b3[(size_t)e * 1024 + c];
    s = s + bb;
    *(f32x4*)&out[((size_t)bnat * TT + (r & 15)) * 1024 + c] = s;
}

extern "C" void kernel_launch(void* const* d_in, const int* in_sizes, int n_in,
                              void* d_out, int out_size, void* d_ws, size_t ws_size,
                              hipStream_t stream) {
    const float* actions   = (const float*)d_in[0];
    const int*   timesteps = (const int*)d_in[1];
    const int*   cat_ids   = (const int*)d_in[2];
    const float* W1        = (const float*)d_in[3];
    const float* b1        = (const float*)d_in[4];
    const float* W2        = (const float*)d_in[5];
    const float* b2        = (const float*)d_in[6];
    const float* W3        = (const float*)d_in[7];
    const float* b3        = (const float*)d_in[8];
    float* out = (float*)d_out;

    int*  meta  = (int*)d_ws;
    u16*  xg    = (u16*)((char*)d_ws + 4096);
    u16*  yg    = (u16*)((char*)d_ws + 4096 + 8ull * 1024 * 1024);
    float* pbuf = (float*)((char*)d_ws + 4096 + 12ull * 1024 * 1024);

    prep_kernel<<<1, 128, 0, stream>>>(cat_ids, meta);
    build_x_kernel<<<128, 256, 0, stream>>>(actions, timesteps, cat_ids, W1, b1, meta, xg);

    // layer 2: K=2048 (4 kc x <=56 slots)
    gemm_rowstream<<<224, 1024, 0, stream>>>(xg, W2, pbuf, meta, 2048, 2048);
    reduce_mid<<<NROWS, 256, 0, stream>>>(pbuf, b2, meta, cat_ids, yg);

    // layer 3: K=1024
    gemm_rowstream<<<224, 1024, 0, stream>>>(yg, W3, pbuf, meta, 1024, 1024);
    reduce_out<<<NROWS, 256, 0, stream>>>(pbuf, b3, meta, cat_ids, out);
}

// Round 10
// 223.813 us; speedup vs baseline: 1.5579x; 1.5579x over previous
//
#include <hip/hip_runtime.h>
#include <hip/hip_bf16.h>
#include <math.h>

#define HIDDEN 1024
#define ADIM 32
#define NEMB 32
#define BB 128
#define TT 16
#define NROWS (BB*TT)   // 2048

typedef float f32x4 __attribute__((ext_vector_type(4)));
typedef short bf16x8 __attribute__((ext_vector_type(8)));
typedef unsigned short u16;

static __device__ __forceinline__ u16 f2bf(float f) {
    union { __hip_bfloat16 h; u16 u; } cv;
    cv.h = __float2bfloat16(f);   // RNE
    return cv.u;
}

static __device__ __forceinline__ void gload_lds16(const void* g, void* l) {
    __builtin_amdgcn_global_load_lds(
        (const __attribute__((address_space(1))) void*)g,
        (__attribute__((address_space(3))) void*)l, 16, 0, 0);
}

// ws layout:
//  [0, 4096)   : meta: [0..31]=cnt, [32..63]=off, [64..191]=blist,
//                [192]=ntiles, [200+4i..]=tiles (row0, rows, e)
//  xg  @ 4096  : 2048 x 2048 bf16 (8MB) grouped rows
//  yg  @ +8MB  : 2048 x 1024 bf16 (4MB) grouped rows

__global__ void prep_kernel(const int* __restrict__ cat, int* __restrict__ meta) {
    __shared__ int c[BB];
    int tid = threadIdx.x;
    if (tid < BB) c[tid] = cat[tid];
    __syncthreads();
    if (tid == 0) {
        int cnt[NEMB];
        for (int e = 0; e < NEMB; e++) cnt[e] = 0;
        for (int b = 0; b < BB; b++) cnt[c[b]]++;
        int off = 0;
        for (int e = 0; e < NEMB; e++) { meta[e] = cnt[e]; meta[32 + e] = off; off += cnt[e]; }
        int pos[NEMB];
        for (int e = 0; e < NEMB; e++) pos[e] = meta[32 + e];
        for (int b = 0; b < BB; b++) { int e = c[b]; meta[64 + pos[e]] = b; pos[e]++; }
        int nt = 0;
        for (int e = 0; e < NEMB; e++) {
            int Me = cnt[e] * TT;
            int base = meta[32 + e] * TT;
            for (int mb = 0; mb * 64 < Me; mb++) {
                int rows = Me - mb * 64; if (rows > 64) rows = 64;
                meta[200 + 4 * nt + 0] = base + mb * 64;
                meta[200 + 4 * nt + 1] = rows;
                meta[200 + 4 * nt + 2] = e;
                nt++;
            }
        }
        meta[192] = nt;   // <= 56
    }
}

// Layer 1 + PE, written grouped as bf16.
__global__ __launch_bounds__(256) void build_x_kernel(
    const float* __restrict__ actions, const int* __restrict__ timesteps,
    const int* __restrict__ cat_ids, const float* __restrict__ W1,
    const float* __restrict__ b1, const int* __restrict__ meta,
    u16* __restrict__ xg)
{
    int sb = blockIdx.x;
    int b  = meta[64 + sb];
    int e  = cat_ids[b];
    int tid = threadIdx.x;

    __shared__ float act[TT][ADIM];
    for (int i = tid; i < TT * ADIM; i += 256)
        act[i / ADIM][i % ADIM] = actions[(size_t)b * TT * ADIM + i];
    __syncthreads();

    float tau = (float)timesteps[b];

    for (int h = tid; h < HIDDEN; h += 256) {
        float acc[TT];
        #pragma unroll
        for (int t = 0; t < TT; t++) acc[t] = 0.f;
        for (int d = 0; d < ADIM; d++) {
            float w = W1[((size_t)e * ADIM + d) * HIDDEN + h];
            #pragma unroll
            for (int t = 0; t < TT; t++) acc[t] += act[t][d] * w;
        }
        float bv = b1[(size_t)e * HIDDEN + h];
        for (int t = 0; t < TT; t++)
            xg[(size_t)(sb * TT + t) * 2048 + h] = f2bf(acc[t] + bv);
    }

    for (int j = tid; j < HIDDEN; j += 256) {
        int i = j >> 1;
        float arg = tau * expf((float)i * -0.017988946f);
        float v = (j & 1) ? cosf(arg) : sinf(arg);
        u16 bv = f2bf(v);
        for (int t = 0; t < TT; t++)
            xg[(size_t)(sb * TT + t) * 2048 + 1024 + j] = bv;
    }
}

// Grouped GEMM with zero-register B staging: global_load_lds f32 directly
// into 4 linear LDS buffers (8KB each), depth-3 counted-vmcnt prefetch,
// unconditional (clamped) loads for static counts, raw lgkm-only barriers.
// Tile 64m x 64n, BK=32/phase, 256 thr (4 waves 2m x 2n).
// bf16 cvt happens on the LDS->reg read path, overlapped with MFMA.
// mode 0: +bias, swish, bf16 grouped. mode 1: +bias, f32 natural scatter.
__global__ __launch_bounds__(256, 4) void gemm_glds(
    const u16* __restrict__ X,        // grouped rows bf16, ld = ldx
    const float* __restrict__ W,      // (NEMB, Kdim, 1024) f32
    const float* __restrict__ bias,   // (NEMB, 1024) f32
    void* __restrict__ outp,
    const int* __restrict__ meta,
    int Kdim, int ldx, int mode)
{
    int bid  = blockIdx.x;
    int nq   = bid & 15;
    int slot = bid >> 4;
    if (slot >= meta[192]) return;
    int row0      = meta[200 + 4 * slot + 0];
    int rowsValid = meta[200 + 4 * slot + 1];
    int e         = meta[200 + 4 * slot + 2];

    int n0 = nq * 64;
    int nP = Kdim >> 5;            // phases of 32k (64 or 32; even)

    __shared__ float Bs[4][2048];  // 4 x [32k][64n] f32, linear (gl_lds layout)

    int tid  = threadIdx.x;
    int lane = tid & 63;
    int wid  = tid >> 6;
    int wm   = wid & 1;            // m-half (32 rows)
    int wn   = wid >> 1;           // n-half (32 cols)
    int l15  = lane & 15;
    int kh   = lane >> 4;

    const float* Wp = W + (size_t)e * Kdim * 1024 + n0;

    // gl_lds mapping: seg S = wid*128 + i*64 + lane; row=S>>4, c16=S&15.
    // LDS byte off = S*16  ->  Bs[buf] holds [row][64 f32] row-major.
    int r0[2], c0[2];
    #pragma unroll
    for (int i = 0; i < 2; i++) {
        int S = wid * 128 + i * 64 + lane;
        r0[i] = S >> 4;
        c0[i] = (S & 15) * 4;
    }
    // wave-uniform LDS dest offsets (bytes) for the two instrs
    int ldst[2] = { (wid * 2 + 0) * 1024, (wid * 2 + 1) * 1024 };

    // A row addresses (clamped)
    int am[2];
    #pragma unroll
    for (int mi = 0; mi < 2; mi++) {
        int m = row0 + wm * 32 + mi * 16 + l15;
        if (m > NROWS - 1) m = NROWS - 1;
        am[mi] = m;
    }

    bf16x8 a0[2], a1[2];
    f32x4 acc[2][2];
    #pragma unroll
    for (int mi = 0; mi < 2; mi++)
        #pragma unroll
        for (int nj = 0; nj < 2; nj++)
            acc[mi][nj] = (f32x4){0.f, 0.f, 0.f, 0.f};

    // clamped-phase helpers (always issue -> static vmcnt counts)
    #define GLB(buf, ph) do { \
        int _p = (ph); if (_p > nP - 1) _p = nP - 1; \
        int _k0 = _p << 5; \
        gload_lds16(&Wp[(size_t)(_k0 + r0[0]) * 1024 + c0[0]], (char*)&Bs[buf][0] + ldst[0]); \
        gload_lds16(&Wp[(size_t)(_k0 + r0[1]) * 1024 + c0[1]], (char*)&Bs[buf][0] + ldst[1]); \
    } while (0)

    #define GLA(ag, ph) do { \
        int _p = (ph); if (_p > nP - 1) _p = nP - 1; \
        _Pragma("unroll") \
        for (int mi = 0; mi < 2; mi++) \
            ag[mi] = *(const bf16x8*)&X[(size_t)am[mi] * ldx + (_p << 5) + kh * 8]; \
    } while (0)

    #define PHASE(p, buf, aCur, aNxt) do { \
        GLA(aNxt, (p) + 1); \
        GLB(((p) + 3) & 3, (p) + 3); \
        asm volatile("s_waitcnt vmcnt(10)" ::: "memory"); \
        __builtin_amdgcn_sched_barrier(0); \
        __builtin_amdgcn_s_barrier(); \
        asm volatile("" ::: "memory"); \
        const float* bp = &Bs[buf][0]; \
        _Pragma("unroll") \
        for (int nj = 0; nj < 2; nj++) { \
            int n = wn * 32 + nj * 16 + l15; \
            bf16x8 bfv; \
            _Pragma("unroll") \
            for (int r = 0; r < 8; r++) \
                bfv[r] = (short)f2bf(bp[(kh * 8 + r) * 64 + n]); \
            _Pragma("unroll") \
            for (int mi = 0; mi < 2; mi++) \
                acc[mi][nj] = __builtin_amdgcn_mfma_f32_16x16x32_bf16(aCur[mi], bfv, acc[mi][nj], 0, 0, 0); \
        } \
        asm volatile("s_waitcnt lgkmcnt(0)" ::: "memory"); \
        __builtin_amdgcn_s_barrier(); \
        asm volatile("" ::: "memory"); \
    } while (0)

    // prologue: 3 B-phases + A(0) in flight
    GLB(0, 0);
    GLB(1, 1);
    GLB(2, 2);
    GLA(a0, 0);

    for (int p = 0; p < nP; p += 2) {
        PHASE(p,     (p) & 3,       a0, a1);
        PHASE(p + 1, (p + 1) & 3,   a1, a0);
    }

    #undef GLB
    #undef GLA
    #undef PHASE

    // fused epilogue
    float bv[2];
    #pragma unroll
    for (int nj = 0; nj < 2; nj++)
        bv[nj] = bias[(size_t)e * 1024 + n0 + wn * 32 + nj * 16 + l15];

    #pragma unroll
    for (int mi = 0; mi < 2; mi++) {
        #pragma unroll
        for (int r = 0; r < 4; r++) {
            int m = wm * 32 + mi * 16 + kh * 4 + r;
            if (m < rowsValid) {
                int grow = row0 + m;
                int col = n0 + wn * 32 + l15;
                if (mode == 0) {
                    u16* dst = (u16*)outp + (size_t)grow * 1024 + col;
                    #pragma unroll
                    for (int nj = 0; nj < 2; nj++) {
                        float h = acc[mi][nj][r] + bv[nj];
                        h = h / (1.f + expf(-h));
                        dst[nj * 16] = f2bf(h);
                    }
                } else {
                    int bnat = meta[64 + (grow >> 4)];
                    float* dst = (float*)outp + ((size_t)bnat * TT + (grow & 15)) * 1024 + col;
                    #pragma unroll
                    for (int nj = 0; nj < 2; nj++)
                        dst[nj * 16] = acc[mi][nj][r] + bv[nj];
                }
            }
        }
    }
}

extern "C" void kernel_launch(void* const* d_in, const int* in_sizes, int n_in,
                              void* d_out, int out_size, void* d_ws, size_t ws_size,
                              hipStream_t stream) {
    const float* actions   = (const float*)d_in[0];
    const int*   timesteps = (const int*)d_in[1];
    const int*   cat_ids   = (const int*)d_in[2];
    const float* W1        = (const float*)d_in[3];
    const float* b1        = (const float*)d_in[4];
    const float* W2        = (const float*)d_in[5];
    const float* b2        = (const float*)d_in[6];
    const float* W3        = (const float*)d_in[7];
    const float* b3        = (const float*)d_in[8];
    float* out = (float*)d_out;

    int* meta = (int*)d_ws;
    u16* xg   = (u16*)((char*)d_ws + 4096);
    u16* yg   = (u16*)((char*)d_ws + 4096 + 8ull * 1024 * 1024);

    prep_kernel<<<1, 128, 0, stream>>>(cat_ids, meta);
    build_x_kernel<<<128, 256, 0, stream>>>(actions, timesteps, cat_ids, W1, b1, meta, xg);

    // layer 2: K=2048, swish, bf16 grouped -> yg
    gemm_glds<<<896, 256, 0, stream>>>(xg, W2, b2, (void*)yg, meta, 2048, 2048, 0);
    // layer 3: K=1024, +bias, f32 natural scatter -> out
    gemm_glds<<<896, 256, 0, stream>>>(yg, W3, b3, (void*)out, meta, 1024, 1024, 1);
}

// Round 11
// 208.212 us; speedup vs baseline: 1.6747x; 1.0749x over previous
//
#include <hip/hip_runtime.h>
#include <hip/hip_bf16.h>
#include <math.h>

#define HIDDEN 1024
#define ADIM 32
#define NEMB 32
#define BB 128
#define TT 16
#define NROWS (BB*TT)   // 2048
#define KSPLIT 4

#define OCT_STRIDE 136    // u16: 128 data + 8 pad
#define GN_STRIDE  1096   // u16: 8*136 + 8 pad
#define BS_U16     (16 * GN_STRIDE)   // 17536 u16 = 35072 B per buffer

typedef float f32x4 __attribute__((ext_vector_type(4)));
typedef short bf16x8 __attribute__((ext_vector_type(8)));
typedef unsigned short u16;

static __device__ __forceinline__ u16 f2bf(float f) {
    union { __hip_bfloat16 h; u16 u; } cv;
    cv.h = __float2bfloat16(f);   // RNE
    return cv.u;
}

// raw barrier: completes LDS ops, leaves global loads in flight (no vmcnt drain)
#define BARRIER() do { \
    asm volatile("s_waitcnt lgkmcnt(0)" ::: "memory"); \
    __builtin_amdgcn_s_barrier(); \
    asm volatile("" ::: "memory"); \
} while (0)

// ws layout:
//  [0, 4096)   : meta ints: [0..31]=cnt, [32..63]=off, [64..191]=blist,
//                [192]=ntiles, [200+4i..]=tiles (row0, rows, e)
//  xg  @ 4096  : 2048 x 2048 bf16 (8MB), grouped rows
//  yg  @ +8MB  : 2048 x 1024 bf16 (4MB), grouped rows
//  pbuf @ +4MB : KSPLIT x 2048 x 1024 f32 (32MB)

__global__ void prep_kernel(const int* __restrict__ cat, int* __restrict__ meta) {
    __shared__ int c[BB];
    int tid = threadIdx.x;
    if (tid < BB) c[tid] = cat[tid];
    __syncthreads();
    if (tid == 0) {
        int cnt[NEMB];
        for (int e = 0; e < NEMB; e++) cnt[e] = 0;
        for (int b = 0; b < BB; b++) cnt[c[b]]++;
        int off = 0;
        for (int e = 0; e < NEMB; e++) { meta[e] = cnt[e]; meta[32 + e] = off; off += cnt[e]; }
        int pos[NEMB];
        for (int e = 0; e < NEMB; e++) pos[e] = meta[32 + e];
        for (int b = 0; b < BB; b++) { int e = c[b]; meta[64 + pos[e]] = b; pos[e]++; }
        int nt = 0;
        for (int e = 0; e < NEMB; e++) {
            int Me = cnt[e] * TT;
            int base = meta[32 + e] * TT;
            for (int mb = 0; mb * 64 < Me; mb++) {
                int rows = Me - mb * 64; if (rows > 64) rows = 64;
                meta[200 + 4 * nt + 0] = base + mb * 64;
                meta[200 + 4 * nt + 1] = rows;
                meta[200 + 4 * nt + 2] = e;
                nt++;
            }
        }
        meta[192] = nt;   // <= 56
    }
}

// Layer 1 + PE, written grouped as bf16.
__global__ __launch_bounds__(256) void build_x_kernel(
    const float* __restrict__ actions, const int* __restrict__ timesteps,
    const int* __restrict__ cat_ids, const float* __restrict__ W1,
    const float* __restrict__ b1, const int* __restrict__ meta,
    u16* __restrict__ xg)
{
    int sb = blockIdx.x;
    int b  = meta[64 + sb];
    int e  = cat_ids[b];
    int tid = threadIdx.x;

    __shared__ float act[TT][ADIM];
    for (int i = tid; i < TT * ADIM; i += 256)
        act[i / ADIM][i % ADIM] = actions[(size_t)b * TT * ADIM + i];
    __syncthreads();

    float tau = (float)timesteps[b];

    for (int h = tid; h < HIDDEN; h += 256) {
        float acc[TT];
        #pragma unroll
        for (int t = 0; t < TT; t++) acc[t] = 0.f;
        for (int d = 0; d < ADIM; d++) {
            float w = W1[((size_t)e * ADIM + d) * HIDDEN + h];
            #pragma unroll
            for (int t = 0; t < TT; t++) acc[t] += act[t][d] * w;
        }
        float bv = b1[(size_t)e * HIDDEN + h];
        for (int t = 0; t < TT; t++)
            xg[(size_t)(sb * TT + t) * 2048 + h] = f2bf(acc[t] + bv);
    }

    for (int j = tid; j < HIDDEN; j += 256) {
        int i = j >> 1;
        float arg = tau * expf((float)i * -0.017988946f);
        float v = (j & 1) ? cosf(arg) : sinf(arg);
        u16 bv = f2bf(v);
        for (int t = 0; t < TT; t++)
            xg[(size_t)(sb * TT + t) * 2048 + 1024 + j] = bv;
    }
}

// Streaming grouped GEMM, split-K partials. r4 structure + A-hoist fix:
// 1D grid: bid = kc + 4*nq + 16*slot. Tile 64m x 256n, BK=64, dbuf LDS,
// 1-deep B reg prefetch (counted-vmcnt WRITEB), A double-buffered in regs
// one K-step ahead (refilled AFTER its consuming COMPUTE) so no A-wait ever
// drains the B stream. All prefetch loads unconditional (clamped tail) ->
// static vmcnt counts. Raw lgkm-only barriers.
__global__ __launch_bounds__(512, 4) void gemm_stream(
    const u16* __restrict__ X,        // grouped rows bf16, ld = ldx
    const float* __restrict__ W,      // (NEMB, Kdim, 1024) f32
    float* __restrict__ pbuf,         // KSPLIT x 2048 x 1024 f32
    const int* __restrict__ meta,
    int Kdim, int ldx)
{
    int bid  = blockIdx.x;
    int kc   = bid & 3;
    int nq   = (bid >> 2) & 3;
    int slot = bid >> 4;
    if (slot >= meta[192]) return;
    int row0      = meta[200 + 4 * slot + 0];
    int rowsValid = meta[200 + 4 * slot + 1];
    int e         = meta[200 + 4 * slot + 2];

    int n0  = nq * 256;
    int KC  = Kdim / KSPLIT;
    int kc0 = kc * KC;
    int nT  = KC >> 6;          // K-steps of 64 (8 for K=2048, 4 for K=1024; even)
    int nTm1 = nT - 1;

    __shared__ u16 Bs[2][BS_U16];

    int tid  = threadIdx.x;
    int lane = tid & 63;
    int wid  = tid >> 6;
    int wm   = wid & 1;     // m-half (32 rows)
    int wn   = wid >> 1;    // n-quarter (64 cols = 4 gn)

    const float* Wp = W + (size_t)e * Kdim * 1024 + n0;

    // B stage map: bn4 = n-quad (0..63), bo = k-octet (0..7); 8 rows f32x4 each.
    int bn4 = tid & 63;
    int bo  = tid >> 6;

    // A row indices (clamped to buffer bounds; invalid rows feed unstored outputs)
    int am[2];
    #pragma unroll
    for (int mi = 0; mi < 2; mi++) {
        int m = row0 + wm * 32 + mi * 16 + (lane & 15);
        if (m > NROWS - 1) m = NROWS - 1;
        am[mi] = m;
    }

    f32x4  bReg[8];             // 1-deep B stage (32 VGPR)
    bf16x8 a0[4], a1[4];        // A frags [h*2+mi], double-buffered (32 VGPR)

    f32x4 acc[2][4];
    #pragma unroll
    for (int mi = 0; mi < 2; mi++)
        #pragma unroll
        for (int g = 0; g < 4; g++)
            acc[mi][g] = (f32x4){0.f, 0.f, 0.f, 0.f};

    #define LOADB(kt) do { \
        int _kt = (kt) > nTm1 ? nTm1 : (kt); \
        int kb = kc0 + _kt * 64 + bo * 8; \
        _Pragma("unroll") \
        for (int r = 0; r < 8; r++) \
            bReg[r] = *(const f32x4*)&Wp[(size_t)(kb + r) * 1024 + bn4 * 4]; \
    } while (0)

    #define LOADA(reg, kt) do { \
        int _kt = (kt) > nTm1 ? nTm1 : (kt); \
        _Pragma("unroll") \
        for (int h = 0; h < 2; h++) \
            _Pragma("unroll") \
            for (int mi = 0; mi < 2; mi++) \
                reg[h * 2 + mi] = *(const bf16x8*)&X[(size_t)am[mi] * ldx + kc0 + _kt * 64 + h * 32 + (lane >> 4) * 8]; \
    } while (0)

    #define WRITEB(c) do { \
        _Pragma("unroll") \
        for (int j = 0; j < 4; j++) { \
            int n = bn4 * 4 + j; \
            bf16x8 v; \
            _Pragma("unroll") \
            for (int r = 0; r < 8; r++) v[r] = (short)f2bf(bReg[r][j]); \
            *(bf16x8*)&Bs[c][(n >> 4) * GN_STRIDE + bo * OCT_STRIDE + (n & 15) * 8] = v; \
        } \
    } while (0)

    #define COMPUTE(c, aP) do { \
        _Pragma("unroll") \
        for (int h = 0; h < 2; h++) { \
            _Pragma("unroll") \
            for (int g = 0; g < 4; g++) { \
                int gn = wn * 4 + g; \
                bf16x8 bf = *(const bf16x8*)&Bs[c][gn * GN_STRIDE + (h * 4 + (lane >> 4)) * OCT_STRIDE + (lane & 15) * 8]; \
                _Pragma("unroll") \
                for (int mi = 0; mi < 2; mi++) \
                    acc[mi][g] = __builtin_amdgcn_mfma_f32_16x16x32_bf16(aP[h * 2 + mi], bf, acc[mi][g], 0, 0, 0); \
            } \
        } \
    } while (0)

    // prologue FIFO: b(0), a0(0), a1(1) -- every later A-wait is pre-satisfied
    // by an earlier WRITEB wait on a younger-or-equal B load group.
    LOADB(0);
    LOADA(a0, 0);
    LOADA(a1, 1);

    for (int kt = 0; kt < nT; kt += 2) {
        // step kt: lds0
        WRITEB(0);                 // waits b(kt); a0/a1 and nothing newer drain
        LOADB(kt + 1);
        BARRIER();
        COMPUTE(0, a0);            // a0 already drained by WRITEB's wait
        LOADA(a0, kt + 2);         // refill after consumption (no WAR stall)
        // step kt+1: lds1
        WRITEB(1);                 // waits b(kt+1); a0(kt+2) stays in flight
        LOADB(kt + 2);
        BARRIER();
        COMPUTE(1, a1);
        LOADA(a1, kt + 3);
    }

    #undef LOADB
    #undef LOADA
    #undef WRITEB
    #undef COMPUTE

    // partial store (row-major pbuf)
    float* pb = pbuf + (size_t)kc * NROWS * 1024;
    int col = n0 + wn * 64 + (lane & 15);
    #pragma unroll
    for (int mi = 0; mi < 2; mi++) {
        #pragma unroll
        for (int r = 0; r < 4; r++) {
            int m = wm * 32 + mi * 16 + ((lane >> 4) << 2) + r;
            if (m < rowsValid) {
                float* dst = pb + (size_t)(row0 + m) * 1024 + col;
                #pragma unroll
                for (int g = 0; g < 4; g++)
                    dst[g * 16] = acc[mi][g][r];
            }
        }
    }
}

// yg = bf16(swish(sum_kc pbuf + b2)), grouped rows
__global__ __launch_bounds__(256) void reduce_mid(
    const float* __restrict__ pbuf, const float* __restrict__ b2,
    const int* __restrict__ meta, const int* __restrict__ cat,
    u16* __restrict__ yg)
{
    int r = blockIdx.x;
    int e = cat[meta[64 + (r >> 4)]];
    int c = threadIdx.x * 4;
    f32x4 s = *(const f32x4*)&pbuf[(size_t)r * 1024 + c];
    #pragma unroll
    for (int kc = 1; kc < KSPLIT; kc++) {
        f32x4 t = *(const f32x4*)&pbuf[(size_t)kc * NROWS * 1024 + (size_t)r * 1024 + c];
        s = s + t;
    }
    f32x4 bb = *(const f32x4*)&b2[(size_t)e * 1024 + c];
    ushort4 o;
    float h0 = s[0] + bb[0]; o.x = f2bf(h0 / (1.f + expf(-h0)));
    float h1 = s[1] + bb[1]; o.y = f2bf(h1 / (1.f + expf(-h1)));
    float h2 = s[2] + bb[2]; o.z = f2bf(h2 / (1.f + expf(-h2)));
    float h3 = s[3] + bb[3]; o.w = f2bf(h3 / (1.f + expf(-h3)));
    *(ushort4*)&yg[(size_t)r * 1024 + c] = o;
}

// out[natural] = sum_kc pbuf + b3
__global__ __launch_bounds__(256) void reduce_out(
    const float* __restrict__ pbuf, const float* __restrict__ b3,
    const int* __restrict__ meta, const int* __restrict__ cat,
    float* __restrict__ out)
{
    int r = blockIdx.x;
    int bnat = meta[64 + (r >> 4)];
    int e = cat[bnat];
    int c = threadIdx.x * 4;
    f32x4 s = *(const f32x4*)&pbuf[(size_t)r * 1024 + c];
    #pragma unroll
    for (int kc = 1; kc < KSPLIT; kc++) {
        f32x4 t = *(const f32x4*)&pbuf[(size_t)kc * NROWS * 1024 + (size_t)r * 1024 + c];
        s = s + t;
    }
    f32x4 bb = *(const f32x4*)&b3[(size_t)e * 1024 + c];
    s = s + bb;
    *(f32x4*)&out[((size_t)bnat * TT + (r & 15)) * 1024 + c] = s;
}

extern "C" void kernel_launch(void* const* d_in, const int* in_sizes, int n_in,
                              void* d_out, int out_size, void* d_ws, size_t ws_size,
                              hipStream_t stream) {
    const float* actions   = (const float*)d_in[0];
    const int*   timesteps = (const int*)d_in[1];
    const int*   cat_ids   = (const int*)d_in[2];
    const float* W1        = (const float*)d_in[3];
    const float* b1        = (const float*)d_in[4];
    const float* W2        = (const float*)d_in[5];
    const float* b2        = (const float*)d_in[6];
    const float* W3        = (const float*)d_in[7];
    const float* b3        = (const float*)d_in[8];
    float* out = (float*)d_out;

    int*  meta  = (int*)d_ws;
    u16*  xg    = (u16*)((char*)d_ws + 4096);
    u16*  yg    = (u16*)((char*)d_ws + 4096 + 8ull * 1024 * 1024);
    float* pbuf = (float*)((char*)d_ws + 4096 + 12ull * 1024 * 1024);

    prep_kernel<<<1, 128, 0, stream>>>(cat_ids, meta);
    build_x_kernel<<<128, 256, 0, stream>>>(actions, timesteps, cat_ids, W1, b1, meta, xg);

    // layer 2: K=2048
    gemm_stream<<<1024, 512, 0, stream>>>(xg, W2, pbuf, meta, 2048, 2048);
    reduce_mid<<<NROWS, 256, 0, stream>>>(pbuf, b2, meta, cat_ids, yg);

    // layer 3: K=1024
    gemm_stream<<<1024, 512, 0, stream>>>(yg, W3, pbuf, meta, 1024, 1024);
    reduce_out<<<NROWS, 256, 0, stream>>>(pbuf, b3, meta, cat_ids, out);
}